// Round 2
// baseline (1169.792 us; speedup 1.0000x reference)
//
#include <hip/hip_runtime.h>
#include <hip/hip_bf16.h>
#include <math.h>

// ---------------- problem constants ----------------
#define BATCH 2
#define SEQ   2048
#define DDIM  2048
#define NH    16
#define HD    128
#define MROWS (BATCH * SEQ)   // 4096

typedef unsigned short u16;
typedef __bf16 bf16x8 __attribute__((ext_vector_type(8)));
typedef float  f32x4  __attribute__((ext_vector_type(4)));

// round-to-nearest-even f32 -> bf16 bits
__device__ __forceinline__ u16 f2bf(float f) {
  unsigned int u = __float_as_uint(f);
  u += 0x7fffu + ((u >> 16) & 1u);
  return (u16)(u >> 16);
}
__device__ __forceinline__ float bf2f(u16 h) {
  return __uint_as_float(((unsigned int)h) << 16);
}

// async global->LDS, 16B per lane; LDS dest is wave-uniform base + lane*16
__device__ __forceinline__ void gload16(const void* g, void* s) {
  __builtin_amdgcn_global_load_lds((const __attribute__((address_space(1))) void*)g,
                                   (__attribute__((address_space(3))) void*)s, 16, 0, 0);
}

// ---------------- X f32 -> (hi, lo) bf16 pair ----------------
__global__ void split_x(const float* __restrict__ in, u16* __restrict__ hi,
                        u16* __restrict__ lo) {
  const int i = blockIdx.x * blockDim.x + threadIdx.x;   // one float4 per thread
  float4 v = ((const float4*)in)[i];
  ushort4 h, l;
  h.x = f2bf(v.x); l.x = f2bf(v.x - bf2f(h.x));
  h.y = f2bf(v.y); l.y = f2bf(v.y - bf2f(h.y));
  h.z = f2bf(v.z); l.z = f2bf(v.z - bf2f(h.z));
  h.w = f2bf(v.w); l.w = f2bf(v.w - bf2f(h.w));
  ((ushort4*)hi)[i] = h;
  ((ushort4*)lo)[i] = l;
}

// ---------------- W [K][N] f32 -> Wt [N][K] bf16 (hi [+ lo]) ----------------
__global__ void transpose_w(const float* __restrict__ W, u16* __restrict__ Wth,
                            u16* __restrict__ Wtl) {
  __shared__ float t[32][33];
  const int tx = threadIdx.x, ty = threadIdx.y;          // 32 x 8
  const int c0 = blockIdx.x * 32, r0 = blockIdx.y * 32;  // c0: n, r0: k
#pragma unroll
  for (int i = 0; i < 4; ++i)
    t[ty + i * 8][tx] = W[(size_t)(r0 + ty + i * 8) * DDIM + c0 + tx];
  __syncthreads();
#pragma unroll
  for (int i = 0; i < 4; ++i) {
    const float v = t[tx][ty + i * 8];
    const u16 h = f2bf(v);
    const size_t idx = (size_t)(c0 + ty + i * 8) * DDIM + r0 + tx;
    Wth[idx] = h;
    if (Wtl) Wtl[idx] = f2bf(v - bf2f(h));
  }
}

// ---------------- V [B*S][D] bf16 -> Vt [B*H][HD][S] bf16 ----------------
__global__ void transpose_v(const u16* __restrict__ V, u16* __restrict__ Vt) {
  __shared__ u16 t[32][33];
  const int tx = threadIdx.x, ty = threadIdx.y;          // 32 x 8
  const int s0 = blockIdx.x * 32;
  const int d0 = blockIdx.y * 32;
  const int bh = blockIdx.z;
  const int b = bh >> 4, h = bh & 15;
#pragma unroll
  for (int i = 0; i < 4; ++i)
    t[ty + i * 8][tx] = V[(size_t)(b * SEQ + s0 + ty + i * 8) * DDIM + h * HD + d0 + tx];
  __syncthreads();
#pragma unroll
  for (int i = 0; i < 4; ++i)
    Vt[((size_t)bh * HD + d0 + ty + i * 8) * SEQ + s0 + tx] = t[tx][ty + i * 8];
}

// ---------------- single-term GEMM: C[M,N] = A[M,K] x Bt[N,K]^T ----------------
// 128x128 tile, BK=64, 4 waves each owning a 64x64 subtile.
// MODE 0: write bf16 C.  MODE 2: write f32 C + bias[col].
template <int MODE>
__global__ __launch_bounds__(256)
void gemm_kernel(const u16* __restrict__ A, const u16* __restrict__ Bt,
                 void* __restrict__ Cout, const float* __restrict__ bias) {
  constexpr int K = DDIM, N = DDIM;
  __shared__ __align__(16) u16 As[128 * 64];
  __shared__ __align__(16) u16 Bs[128 * 64];
  const int tid = threadIdx.x;
  const int wave = tid >> 6;
  const int lane = tid & 63;
  const int lr = lane & 15, lg = lane >> 4;
  const int bm = blockIdx.y * 128, bn = blockIdx.x * 128;
  const int wr = wave >> 1, wc = wave & 1;

  f32x4 acc[4][4] = {};

  const int srow = wave * 32 + (lane >> 3);
  const int scol = (lane & 7) * 8;
  const u16* Ag = A  + (size_t)(bm + srow) * K + scol;
  const u16* Bg = Bt + (size_t)(bn + srow) * K + scol;

  for (int k0 = 0; k0 < K; k0 += 64) {
    __syncthreads();
#pragma unroll
    for (int it = 0; it < 4; ++it) {
      gload16(Ag + (size_t)it * 8 * K + k0, &As[(wave * 32 + it * 8) * 64]);
      gload16(Bg + (size_t)it * 8 * K + k0, &Bs[(wave * 32 + it * 8) * 64]);
    }
    __syncthreads();
#pragma unroll
    for (int kk = 0; kk < 64; kk += 32) {
      bf16x8 af[4], bfr[4];
#pragma unroll
      for (int i = 0; i < 4; ++i)
        af[i] = *(const bf16x8*)&As[(wr * 64 + i * 16 + lr) * 64 + kk + lg * 8];
#pragma unroll
      for (int j = 0; j < 4; ++j)
        bfr[j] = *(const bf16x8*)&Bs[(wc * 64 + j * 16 + lr) * 64 + kk + lg * 8];
#pragma unroll
      for (int i = 0; i < 4; ++i)
#pragma unroll
        for (int j = 0; j < 4; ++j)
          acc[i][j] = __builtin_amdgcn_mfma_f32_16x16x32_bf16(af[i], bfr[j], acc[i][j], 0, 0, 0);
    }
  }

#pragma unroll
  for (int i = 0; i < 4; ++i) {
    const int row0 = bm + wr * 64 + i * 16 + lg * 4;
#pragma unroll
    for (int j = 0; j < 4; ++j) {
      const int col = bn + wc * 64 + j * 16 + lr;
#pragma unroll
      for (int e = 0; e < 4; ++e) {
        const int row = row0 + e;
        const float v = acc[i][j][e];
        if constexpr (MODE == 0) {
          ((u16*)Cout)[(size_t)row * N + col] = f2bf(v);
        } else {
          ((float*)Cout)[(size_t)row * N + col] = v + bias[col];
        }
      }
    }
  }
}

// ---------------- 3-term split GEMM: C = (Ah+Al) x (Bh+Bl)^T, drop Al*Bl ----------------
// near-fp32 accuracy from bf16 MFMA. Writes bf16 hi (and optionally lo residual).
template <bool WRITE_LO>
__global__ __launch_bounds__(256)
void gemm3_kernel(const u16* __restrict__ Ah, const u16* __restrict__ Al,
                  const u16* __restrict__ Bh, const u16* __restrict__ Bl,
                  u16* __restrict__ Ch, u16* __restrict__ Cl) {
  constexpr int K = DDIM, N = DDIM;
  __shared__ __align__(16) u16 Ash[128 * 64];
  __shared__ __align__(16) u16 Asl[128 * 64];
  __shared__ __align__(16) u16 Bsh[128 * 64];
  __shared__ __align__(16) u16 Bsl[128 * 64];
  const int tid = threadIdx.x;
  const int wave = tid >> 6;
  const int lane = tid & 63;
  const int lr = lane & 15, lg = lane >> 4;
  const int bm = blockIdx.y * 128, bn = blockIdx.x * 128;
  const int wr = wave >> 1, wc = wave & 1;

  f32x4 acc[4][4] = {};

  const int srow = wave * 32 + (lane >> 3);
  const int scol = (lane & 7) * 8;
  const size_t aoff = (size_t)(bm + srow) * K + scol;
  const size_t boff = (size_t)(bn + srow) * K + scol;

  for (int k0 = 0; k0 < K; k0 += 64) {
    __syncthreads();
#pragma unroll
    for (int it = 0; it < 4; ++it) {
      const size_t ro = (size_t)it * 8 * K + k0;
      const int ls = (wave * 32 + it * 8) * 64;
      gload16(Ah + aoff + ro, &Ash[ls]);
      gload16(Al + aoff + ro, &Asl[ls]);
      gload16(Bh + boff + ro, &Bsh[ls]);
      gload16(Bl + boff + ro, &Bsl[ls]);
    }
    __syncthreads();
#pragma unroll
    for (int kk = 0; kk < 64; kk += 32) {
      bf16x8 ah[4], al[4], bh[4], bl[4];
#pragma unroll
      for (int i = 0; i < 4; ++i) {
        const int off = (wr * 64 + i * 16 + lr) * 64 + kk + lg * 8;
        ah[i] = *(const bf16x8*)&Ash[off];
        al[i] = *(const bf16x8*)&Asl[off];
      }
#pragma unroll
      for (int j = 0; j < 4; ++j) {
        const int off = (wc * 64 + j * 16 + lr) * 64 + kk + lg * 8;
        bh[j] = *(const bf16x8*)&Bsh[off];
        bl[j] = *(const bf16x8*)&Bsl[off];
      }
#pragma unroll
      for (int i = 0; i < 4; ++i)
#pragma unroll
        for (int j = 0; j < 4; ++j) {
          acc[i][j] = __builtin_amdgcn_mfma_f32_16x16x32_bf16(ah[i], bh[j], acc[i][j], 0, 0, 0);
          acc[i][j] = __builtin_amdgcn_mfma_f32_16x16x32_bf16(ah[i], bl[j], acc[i][j], 0, 0, 0);
          acc[i][j] = __builtin_amdgcn_mfma_f32_16x16x32_bf16(al[i], bh[j], acc[i][j], 0, 0, 0);
        }
    }
  }

#pragma unroll
  for (int i = 0; i < 4; ++i) {
    const int row0 = bm + wr * 64 + i * 16 + lg * 4;
#pragma unroll
    for (int j = 0; j < 4; ++j) {
      const int col = bn + wc * 64 + j * 16 + lr;
#pragma unroll
      for (int e = 0; e < 4; ++e) {
        const float v = acc[i][j][e];
        const u16 h = f2bf(v);
        const size_t idx = (size_t)(row0 + e) * N + col;
        Ch[idx] = h;
        if constexpr (WRITE_LO) Cl[idx] = f2bf(v - bf2f(h));
      }
    }
  }
}

// ---------------- causal flash attention (2-term scores) ----------------
// grid (S/64, B*H), 256 threads = 4 independent waves; wave owns 16 q rows.
// scores = qh*(kh + kl) via two MFMAs -> removes K-storage rounding from scores.
__global__ __launch_bounds__(256)
void attn_kernel(const u16* __restrict__ Qh, const u16* __restrict__ Kh,
                 const u16* __restrict__ Kl, const u16* __restrict__ Vt,
                 u16* __restrict__ ctx) {
  __shared__ __align__(16) u16 P_lds[4][16 * 32];
  const int tid = threadIdx.x;
  const int wave = tid >> 6, lane = tid & 63;
  const int lr = lane & 15, lg = lane >> 4;
  const int q0 = blockIdx.x * 64;
  const int bh = blockIdx.y;
  const int b = bh >> 4, h = bh & 15;
  const int qw = q0 + wave * 16;
  const float NEG_INF = -__builtin_inff();

  bf16x8 qf[4];
#pragma unroll
  for (int kk = 0; kk < 4; ++kk)
    qf[kk] = *(const bf16x8*)&Qh[(size_t)(b * SEQ + qw + lr) * DDIM + h * HD + kk * 32 + lg * 8];

  float m[4], l[4];
#pragma unroll
  for (int e = 0; e < 4; ++e) { m[e] = NEG_INF; l[e] = 0.f; }
  f32x4 o[8] = {};

  const u16* Vh = Vt + (size_t)bh * HD * SEQ;
  const int kmax = qw + 15;
  for (int k0 = 0; k0 <= kmax; k0 += 32) {
    f32x4 s[2] = {};
#pragma unroll
    for (int fc = 0; fc < 2; ++fc) {
#pragma unroll
      for (int kk = 0; kk < 4; ++kk) {
        const size_t kidx = (size_t)(b * SEQ + k0 + fc * 16 + lr) * DDIM + h * HD + kk * 32 + lg * 8;
        bf16x8 kfh = *(const bf16x8*)&Kh[kidx];
        bf16x8 kfl = *(const bf16x8*)&Kl[kidx];
        s[fc] = __builtin_amdgcn_mfma_f32_16x16x32_bf16(qf[kk], kfh, s[fc], 0, 0, 0);
        s[fc] = __builtin_amdgcn_mfma_f32_16x16x32_bf16(qf[kk], kfl, s[fc], 0, 0, 0);
      }
    }
    // causal mask + online softmax (row = qw + 4*lg + e, key = k0 + fc*16 + lr)
#pragma unroll
    for (int e = 0; e < 4; ++e) {
      const int row = qw + lg * 4 + e;
#pragma unroll
      for (int fc = 0; fc < 2; ++fc) {
        const int key = k0 + fc * 16 + lr;
        if (key > row) s[fc][e] = NEG_INF;
      }
      float rm = fmaxf(s[0][e], s[1][e]);
      rm = fmaxf(rm, __shfl_xor(rm, 1));
      rm = fmaxf(rm, __shfl_xor(rm, 2));
      rm = fmaxf(rm, __shfl_xor(rm, 4));
      rm = fmaxf(rm, __shfl_xor(rm, 8));
      const float mn = fmaxf(m[e], rm);
      const float al = __expf(m[e] - mn);
      const float p0 = __expf(s[0][e] - mn);
      const float p1 = __expf(s[1][e] - mn);
      s[0][e] = p0; s[1][e] = p1;
      float rs = p0 + p1;
      rs += __shfl_xor(rs, 1);
      rs += __shfl_xor(rs, 2);
      rs += __shfl_xor(rs, 4);
      rs += __shfl_xor(rs, 8);
      l[e] = l[e] * al + rs;
      m[e] = mn;
#pragma unroll
      for (int db = 0; db < 8; ++db) o[db][e] *= al;
    }
    // P (D-layout) -> LDS -> reload in A-operand layout (wave-private region)
#pragma unroll
    for (int fc = 0; fc < 2; ++fc)
#pragma unroll
      for (int e = 0; e < 4; ++e)
        P_lds[wave][(lg * 4 + e) * 32 + fc * 16 + lr] = f2bf(s[fc][e]);
    __builtin_amdgcn_wave_barrier();
    bf16x8 pf = *(const bf16x8*)&P_lds[wave][lr * 32 + lg * 8];
    __builtin_amdgcn_wave_barrier();
#pragma unroll
    for (int db = 0; db < 8; ++db) {
      bf16x8 vf = *(const bf16x8*)&Vh[(size_t)(db * 16 + lr) * SEQ + k0 + lg * 8];
      o[db] = __builtin_amdgcn_mfma_f32_16x16x32_bf16(pf, vf, o[db], 0, 0, 0);
    }
  }
#pragma unroll
  for (int db = 0; db < 8; ++db)
#pragma unroll
    for (int e = 0; e < 4; ++e) {
      const float v = o[db][e] / l[e];
      ctx[(size_t)(b * SEQ + qw + lg * 4 + e) * DDIM + h * HD + db * 16 + lr] = f2bf(v);
    }
}

// ---------------- launch ----------------
extern "C" void kernel_launch(void* const* d_in, const int* in_sizes, int n_in,
                              void* d_out, int out_size, void* d_ws, size_t ws_size,
                              hipStream_t stream) {
  const float* X  = (const float*)d_in[0];
  const float* Wq = (const float*)d_in[1];
  const float* Wk = (const float*)d_in[2];
  const float* Wv = (const float*)d_in[3];
  const float* Wo = (const float*)d_in[4];
  const float* bo = (const float*)d_in[5];
  float* out = (float*)d_out;

  const size_t SZ_XD = (size_t)MROWS * DDIM * 2;  // 16 MiB
  const size_t SZ_W  = (size_t)DDIM * DDIM * 2;   // 8 MiB

  char* p = (char*)d_ws;
  auto alloc = [&](size_t bytes) {
    char* r = p;
    p += (bytes + 255) & ~(size_t)255;
    return r;
  };
  // total: 7 x 16 MiB = 112 MiB (same footprint as round-1's proven layout)
  u16* Xh  = (u16*)alloc(SZ_XD);
  u16* Xl  = (u16*)alloc(SZ_XD);
  u16* Wbh = (u16*)alloc(SZ_W);   // W staging region, reused per weight
  u16* Wbl = (u16*)alloc(SZ_W);
  u16* Qh  = (u16*)alloc(SZ_XD);
  u16* Kh  = (u16*)alloc(SZ_XD);
  u16* Kl  = (u16*)alloc(SZ_XD);
  u16* Vb  = (u16*)alloc(SZ_XD);
  u16* Vt  = Xh;   // Xh dead after V projection; transpose_v runs after
  u16* ctx = Qh;   // each attn block reads exactly the Q panel it overwrites

  split_x<<<(MROWS * DDIM) / 1024, 256, 0, stream>>>(X, Xh, Xl);

  dim3 tb(32, 8);
  dim3 gg(DDIM / 128, MROWS / 128);

  transpose_w<<<dim3(64, 64), tb, 0, stream>>>(Wq, Wbh, Wbl);
  gemm3_kernel<false><<<gg, 256, 0, stream>>>(Xh, Xl, Wbh, Wbl, Qh, nullptr);

  transpose_w<<<dim3(64, 64), tb, 0, stream>>>(Wk, Wbh, Wbl);
  gemm3_kernel<true><<<gg, 256, 0, stream>>>(Xh, Xl, Wbh, Wbl, Kh, Kl);

  transpose_w<<<dim3(64, 64), tb, 0, stream>>>(Wv, Wbh, nullptr);
  gemm_kernel<0><<<gg, 256, 0, stream>>>(Xh, Wbh, Vb, nullptr);

  transpose_v<<<dim3(SEQ / 32, HD / 32, BATCH * NH), tb, 0, stream>>>(Vb, Vt);

  transpose_w<<<dim3(64, 64), tb, 0, stream>>>(Wo, Wbh, nullptr);

  attn_kernel<<<dim3(SEQ / 64, BATCH * NH), 256, 0, stream>>>(Qh, Kh, Kl, Vt, ctx);

  gemm_kernel<2><<<gg, 256, 0, stream>>>(ctx, Wbh, out, bo);
}

// Round 3
// 633.926 us; speedup vs baseline: 1.8453x; 1.8453x over previous
//
#include <hip/hip_runtime.h>
#include <hip/hip_bf16.h>
#include <math.h>

// ---------------- problem constants ----------------
#define BATCH 2
#define SEQ   2048
#define DDIM  2048
#define NH    16
#define HD    128
#define MROWS (BATCH * SEQ)   // 4096

typedef unsigned short u16;
typedef __bf16 bf16x8 __attribute__((ext_vector_type(8)));
typedef float  f32x4  __attribute__((ext_vector_type(4)));

// round-to-nearest-even f32 -> bf16 bits
__device__ __forceinline__ u16 f2bf(float f) {
  unsigned int u = __float_as_uint(f);
  u += 0x7fffu + ((u >> 16) & 1u);
  return (u16)(u >> 16);
}
__device__ __forceinline__ float bf2f(u16 h) {
  return __uint_as_float(((unsigned int)h) << 16);
}

// async global->LDS, 16B per lane; LDS dest is wave-uniform base + lane*16
__device__ __forceinline__ void gload16(const void* g, void* s) {
  __builtin_amdgcn_global_load_lds((const __attribute__((address_space(1))) void*)g,
                                   (__attribute__((address_space(3))) void*)s, 16, 0, 0);
}

// ---------------- X f32 -> (hi, lo) bf16 pair ----------------
__global__ void split_x(const float* __restrict__ in, u16* __restrict__ hi,
                        u16* __restrict__ lo) {
  const int i = blockIdx.x * blockDim.x + threadIdx.x;   // one float4 per thread
  float4 v = ((const float4*)in)[i];
  ushort4 h, l;
  h.x = f2bf(v.x); l.x = f2bf(v.x - bf2f(h.x));
  h.y = f2bf(v.y); l.y = f2bf(v.y - bf2f(h.y));
  h.z = f2bf(v.z); l.z = f2bf(v.z - bf2f(h.z));
  h.w = f2bf(v.w); l.w = f2bf(v.w - bf2f(h.w));
  ((ushort4*)hi)[i] = h;
  ((ushort4*)lo)[i] = l;
}

// ---------------- W [K][N] f32 -> Wt [N][K] bf16 (hi [+ lo]) ----------------
__global__ void transpose_w(const float* __restrict__ W, u16* __restrict__ Wth,
                            u16* __restrict__ Wtl) {
  __shared__ float t[32][33];
  const int tx = threadIdx.x, ty = threadIdx.y;          // 32 x 8
  const int c0 = blockIdx.x * 32, r0 = blockIdx.y * 32;  // c0: n, r0: k
#pragma unroll
  for (int i = 0; i < 4; ++i)
    t[ty + i * 8][tx] = W[(size_t)(r0 + ty + i * 8) * DDIM + c0 + tx];
  __syncthreads();
#pragma unroll
  for (int i = 0; i < 4; ++i) {
    const float v = t[tx][ty + i * 8];
    const u16 h = f2bf(v);
    const size_t idx = (size_t)(c0 + ty + i * 8) * DDIM + r0 + tx;
    Wth[idx] = h;
    if (Wtl) Wtl[idx] = f2bf(v - bf2f(h));
  }
}

// ---------------- V [B*S][D] bf16 -> Vt [B*H][HD][S] bf16 ----------------
__global__ void transpose_v(const u16* __restrict__ V, u16* __restrict__ Vt) {
  __shared__ u16 t[32][33];
  const int tx = threadIdx.x, ty = threadIdx.y;          // 32 x 8
  const int s0 = blockIdx.x * 32;
  const int d0 = blockIdx.y * 32;
  const int bh = blockIdx.z;
  const int b = bh >> 4, h = bh & 15;
#pragma unroll
  for (int i = 0; i < 4; ++i)
    t[ty + i * 8][tx] = V[(size_t)(b * SEQ + s0 + ty + i * 8) * DDIM + h * HD + d0 + tx];
  __syncthreads();
#pragma unroll
  for (int i = 0; i < 4; ++i)
    Vt[((size_t)bh * HD + d0 + ty + i * 8) * SEQ + s0 + tx] = t[tx][ty + i * 8];
}

// ---------------- single-term GEMM: C[M,N] = A[M,K] x Bt[N,K]^T ----------------
template <int MODE>
__global__ __launch_bounds__(256)
void gemm_kernel(const u16* __restrict__ A, const u16* __restrict__ Bt,
                 void* __restrict__ Cout, const float* __restrict__ bias) {
  constexpr int K = DDIM, N = DDIM;
  __shared__ __align__(16) u16 As[128 * 64];
  __shared__ __align__(16) u16 Bs[128 * 64];
  const int tid = threadIdx.x;
  const int wave = tid >> 6;
  const int lane = tid & 63;
  const int lr = lane & 15, lg = lane >> 4;
  const int bm = blockIdx.y * 128, bn = blockIdx.x * 128;
  const int wr = wave >> 1, wc = wave & 1;

  f32x4 acc[4][4] = {};

  const int srow = wave * 32 + (lane >> 3);
  const int scol = (lane & 7) * 8;
  const u16* Ag = A  + (size_t)(bm + srow) * K + scol;
  const u16* Bg = Bt + (size_t)(bn + srow) * K + scol;

  for (int k0 = 0; k0 < K; k0 += 64) {
    __syncthreads();
#pragma unroll
    for (int it = 0; it < 4; ++it) {
      gload16(Ag + (size_t)it * 8 * K + k0, &As[(wave * 32 + it * 8) * 64]);
      gload16(Bg + (size_t)it * 8 * K + k0, &Bs[(wave * 32 + it * 8) * 64]);
    }
    __syncthreads();
#pragma unroll
    for (int kk = 0; kk < 64; kk += 32) {
      bf16x8 af[4], bfr[4];
#pragma unroll
      for (int i = 0; i < 4; ++i)
        af[i] = *(const bf16x8*)&As[(wr * 64 + i * 16 + lr) * 64 + kk + lg * 8];
#pragma unroll
      for (int j = 0; j < 4; ++j)
        bfr[j] = *(const bf16x8*)&Bs[(wc * 64 + j * 16 + lr) * 64 + kk + lg * 8];
#pragma unroll
      for (int i = 0; i < 4; ++i)
#pragma unroll
        for (int j = 0; j < 4; ++j)
          acc[i][j] = __builtin_amdgcn_mfma_f32_16x16x32_bf16(af[i], bfr[j], acc[i][j], 0, 0, 0);
    }
  }

#pragma unroll
  for (int i = 0; i < 4; ++i) {
    const int row0 = bm + wr * 64 + i * 16 + lg * 4;
#pragma unroll
    for (int j = 0; j < 4; ++j) {
      const int col = bn + wc * 64 + j * 16 + lr;
#pragma unroll
      for (int e = 0; e < 4; ++e) {
        const int row = row0 + e;
        const float v = acc[i][j][e];
        if constexpr (MODE == 0) {
          ((u16*)Cout)[(size_t)row * N + col] = f2bf(v);
        } else {
          ((float*)Cout)[(size_t)row * N + col] = v + bias[col];
        }
      }
    }
  }
}

// ---------------- 3-term split GEMM: C = (Ah+Al) x (Bh+Bl)^T, drop Al*Bl ----------------
template <bool WRITE_LO>
__global__ __launch_bounds__(256)
void gemm3_kernel(const u16* __restrict__ Ah, const u16* __restrict__ Al,
                  const u16* __restrict__ Bh, const u16* __restrict__ Bl,
                  u16* __restrict__ Ch, u16* __restrict__ Cl) {
  constexpr int K = DDIM, N = DDIM;
  __shared__ __align__(16) u16 Ash[128 * 64];
  __shared__ __align__(16) u16 Asl[128 * 64];
  __shared__ __align__(16) u16 Bsh[128 * 64];
  __shared__ __align__(16) u16 Bsl[128 * 64];
  const int tid = threadIdx.x;
  const int wave = tid >> 6;
  const int lane = tid & 63;
  const int lr = lane & 15, lg = lane >> 4;
  const int bm = blockIdx.y * 128, bn = blockIdx.x * 128;
  const int wr = wave >> 1, wc = wave & 1;

  f32x4 acc[4][4] = {};

  const int srow = wave * 32 + (lane >> 3);
  const int scol = (lane & 7) * 8;
  const size_t aoff = (size_t)(bm + srow) * K + scol;
  const size_t boff = (size_t)(bn + srow) * K + scol;

  for (int k0 = 0; k0 < K; k0 += 64) {
    __syncthreads();
#pragma unroll
    for (int it = 0; it < 4; ++it) {
      const size_t ro = (size_t)it * 8 * K + k0;
      const int ls = (wave * 32 + it * 8) * 64;
      gload16(Ah + aoff + ro, &Ash[ls]);
      gload16(Al + aoff + ro, &Asl[ls]);
      gload16(Bh + boff + ro, &Bsh[ls]);
      gload16(Bl + boff + ro, &Bsl[ls]);
    }
    __syncthreads();
#pragma unroll
    for (int kk = 0; kk < 64; kk += 32) {
      bf16x8 ah[4], al[4], bh[4], bl[4];
#pragma unroll
      for (int i = 0; i < 4; ++i) {
        const int off = (wr * 64 + i * 16 + lr) * 64 + kk + lg * 8;
        ah[i] = *(const bf16x8*)&Ash[off];
        al[i] = *(const bf16x8*)&Asl[off];
      }
#pragma unroll
      for (int j = 0; j < 4; ++j) {
        const int off = (wc * 64 + j * 16 + lr) * 64 + kk + lg * 8;
        bh[j] = *(const bf16x8*)&Bsh[off];
        bl[j] = *(const bf16x8*)&Bsl[off];
      }
#pragma unroll
      for (int i = 0; i < 4; ++i)
#pragma unroll
        for (int j = 0; j < 4; ++j) {
          acc[i][j] = __builtin_amdgcn_mfma_f32_16x16x32_bf16(ah[i], bh[j], acc[i][j], 0, 0, 0);
          acc[i][j] = __builtin_amdgcn_mfma_f32_16x16x32_bf16(ah[i], bl[j], acc[i][j], 0, 0, 0);
          acc[i][j] = __builtin_amdgcn_mfma_f32_16x16x32_bf16(al[i], bh[j], acc[i][j], 0, 0, 0);
        }
    }
  }

#pragma unroll
  for (int i = 0; i < 4; ++i) {
    const int row0 = bm + wr * 64 + i * 16 + lg * 4;
#pragma unroll
    for (int j = 0; j < 4; ++j) {
      const int col = bn + wc * 64 + j * 16 + lr;
#pragma unroll
      for (int e = 0; e < 4; ++e) {
        const float v = acc[i][j][e];
        const u16 h = f2bf(v);
        const size_t idx = (size_t)(row0 + e) * N + col;
        Ch[idx] = h;
        if constexpr (WRITE_LO) Cl[idx] = f2bf(v - bf2f(h));
      }
    }
  }
}

// ---------------- causal flash attention (LDS-staged, 2-phase pipeline) ----------------
// 1024 blocks x 256 threads (4 waves, 16 q-rows each). Per 32-key tile:
// prefetch next tile's Kh/Kl/V into the other LDS buffer (global_load_lds),
// compute QK^T (2-term) + online softmax + PV from current buffer, one barrier.
// LDS tiles XOR-swizzled (pre-swizzled global source + swizzled read).
__global__ __launch_bounds__(256)
void attn_kernel(const u16* __restrict__ Qh, const u16* __restrict__ Khp,
                 const u16* __restrict__ Klp, const u16* __restrict__ Vt,
                 u16* __restrict__ ctx) {
  __shared__ __align__(16) u16 Ksh[2][32 * 128];   // [key][d]   rows 256B, swz (r&7)<<4
  __shared__ __align__(16) u16 Ksl[2][32 * 128];
  __shared__ __align__(16) u16 Vs [2][128 * 32];   // [d][key]   rows 64B,  swz (d&3)<<4
  __shared__ __align__(16) u16 P_lds[4][16 * 32];  // [q][key]   rows 64B,  swz (q&3)<<4
  const int tid = threadIdx.x;
  const int wave = tid >> 6, lane = tid & 63;
  const int lr = lane & 15, lg = lane >> 4;

  // chunked XCD swizzle (1024 blocks, 8 XCDs -> 128-block chunks = 4 heads/XCD)
  // + reversed q-block order so long (high-q0) blocks dispatch first.
  const int id = blockIdx.y * 32 + blockIdx.x;
  const int nid = (id & 7) * 128 + (id >> 3);
  const int bh = nid >> 5;
  const int qb = 31 - (nid & 31);
  const int q0 = qb * 64;
  const int b = bh >> 4, h = bh & 15;
  const int qw = q0 + wave * 16;
  const float NEG_INF = -__builtin_inff();

  const u16* Kg = Khp + (size_t)b * SEQ * DDIM + h * HD;
  const u16* Lg = Klp + (size_t)b * SEQ * DDIM + h * HD;
  const u16* Vg = Vt + (size_t)bh * HD * SEQ;

  // Q fragments in registers: A[q=lr][k=kk*32+lg*8+e]
  bf16x8 qf[4];
#pragma unroll
  for (int kk = 0; kk < 4; ++kk)
    qf[kk] = *(const bf16x8*)&Qh[(size_t)(b * SEQ + qw + lr) * DDIM + h * HD + kk * 32 + lg * 8];

  // staging geometry (per lane): K rows 256B, V rows 64B
  const int krow0 = wave * 4 + (lane >> 4);        // + it*16
  const int kcolb = (lane & 15) << 4;              // byte in K row
  const int vrow0 = wave * 16 + (lane >> 2);       // + it*64
  const int vcolb = (lane & 3) << 4;               // byte in V row

  auto STAGE = [&](int buf, int t) {
    const int kbase = t * 32;
#pragma unroll
    for (int it = 0; it < 2; ++it) {
      const int r = it * 16 + krow0;
      const int c = (kcolb ^ ((r & 7) << 4)) >> 1;           // element col [0,128)
      const size_t g = (size_t)(kbase + r) * DDIM + c;
      gload16(Kg + g, &Ksh[buf][it * 2048 + wave * 512]);
      gload16(Lg + g, &Ksl[buf][it * 2048 + wave * 512]);
    }
#pragma unroll
    for (int it = 0; it < 2; ++it) {
      const int d = it * 64 + vrow0;
      const int c = (vcolb ^ ((d & 3) << 4)) >> 1;           // element col [0,32)
      gload16(Vg + (size_t)d * SEQ + kbase + c, &Vs[buf][it * 2048 + wave * 512]);
    }
  };

  float m[4], l[4];
#pragma unroll
  for (int e = 0; e < 4; ++e) { m[e] = NEG_INF; l[e] = 0.f; }
  f32x4 o[8] = {};

  const int nt = 2 * qb + 2;   // 32-key tiles covering keys 0 .. q0+63
  int cur = 0;
  STAGE(0, 0);
  __syncthreads();

  for (int t = 0; t < nt; ++t) {
    if (t + 1 < nt) STAGE(cur ^ 1, t + 1);
    const int k0 = t * 32;
    if (k0 <= qw + 15) {      // wave-uniform: skip fully-masked tiles
      // ---- QK^T (2-term) from LDS ----
      f32x4 s[2] = {};
#pragma unroll
      for (int fc = 0; fc < 2; ++fc) {
        const int r = fc * 16 + lr;
        const int sw = (r & 7) << 4;
#pragma unroll
        for (int kk = 0; kk < 4; ++kk) {
          const int idx = r * 128 + (((kk * 64 + lg * 16) ^ sw) >> 1);
          bf16x8 kfh = *(const bf16x8*)&Ksh[cur][idx];
          bf16x8 kfl = *(const bf16x8*)&Ksl[cur][idx];
          s[fc] = __builtin_amdgcn_mfma_f32_16x16x32_bf16(qf[kk], kfh, s[fc], 0, 0, 0);
          s[fc] = __builtin_amdgcn_mfma_f32_16x16x32_bf16(qf[kk], kfl, s[fc], 0, 0, 0);
        }
      }
      // ---- causal mask + online softmax (row = qw+4*lg+e, key = k0+fc*16+lr) ----
#pragma unroll
      for (int e = 0; e < 4; ++e) {
        const int row = qw + lg * 4 + e;
#pragma unroll
        for (int fc = 0; fc < 2; ++fc) {
          const int key = k0 + fc * 16 + lr;
          if (key > row) s[fc][e] = NEG_INF;
        }
        float rm = fmaxf(s[0][e], s[1][e]);
        rm = fmaxf(rm, __shfl_xor(rm, 1));
        rm = fmaxf(rm, __shfl_xor(rm, 2));
        rm = fmaxf(rm, __shfl_xor(rm, 4));
        rm = fmaxf(rm, __shfl_xor(rm, 8));
        const float mn = fmaxf(m[e], rm);
        const float al = __expf(m[e] - mn);
        const float p0 = __expf(s[0][e] - mn);
        const float p1 = __expf(s[1][e] - mn);
        s[0][e] = p0; s[1][e] = p1;
        float rs = p0 + p1;
        rs += __shfl_xor(rs, 1);
        rs += __shfl_xor(rs, 2);
        rs += __shfl_xor(rs, 4);
        rs += __shfl_xor(rs, 8);
        l[e] = l[e] * al + rs;
        m[e] = mn;
#pragma unroll
        for (int db = 0; db < 8; ++db) o[db][e] *= al;
      }
      // ---- P (D-layout) -> LDS (swizzled) -> A-operand layout ----
#pragma unroll
      for (int fc = 0; fc < 2; ++fc)
#pragma unroll
        for (int e = 0; e < 4; ++e) {
          const int q = lg * 4 + e;
          const int kb = ((fc * 16 + lr) * 2) ^ ((q & 3) << 4);
          P_lds[wave][q * 32 + (kb >> 1)] = f2bf(s[fc][e]);
        }
      __builtin_amdgcn_wave_barrier();
      bf16x8 pf = *(const bf16x8*)&P_lds[wave][lr * 32 + (((lg * 16) ^ ((lr & 3) << 4)) >> 1)];
      __builtin_amdgcn_wave_barrier();
      // ---- PV from LDS V tile ----
#pragma unroll
      for (int db = 0; db < 8; ++db) {
        const int d = db * 16 + lr;
        const int idx = d * 32 + (((lg * 16) ^ ((d & 3) << 4)) >> 1);
        bf16x8 vf = *(const bf16x8*)&Vs[cur][idx];
        o[db] = __builtin_amdgcn_mfma_f32_16x16x32_bf16(pf, vf, o[db], 0, 0, 0);
      }
    }
    __syncthreads();   // drains prefetch vmcnt + protects LDS buffer reuse
    cur ^= 1;
  }

  // epilogue: ctx = o / l
#pragma unroll
  for (int db = 0; db < 8; ++db)
#pragma unroll
    for (int e = 0; e < 4; ++e) {
      const float v = o[db][e] / l[e];
      ctx[(size_t)(b * SEQ + qw + lg * 4 + e) * DDIM + h * HD + db * 16 + lr] = f2bf(v);
    }
}

// ---------------- launch ----------------
extern "C" void kernel_launch(void* const* d_in, const int* in_sizes, int n_in,
                              void* d_out, int out_size, void* d_ws, size_t ws_size,
                              hipStream_t stream) {
  const float* X  = (const float*)d_in[0];
  const float* Wq = (const float*)d_in[1];
  const float* Wk = (const float*)d_in[2];
  const float* Wv = (const float*)d_in[3];
  const float* Wo = (const float*)d_in[4];
  const float* bo = (const float*)d_in[5];
  float* out = (float*)d_out;

  const size_t SZ_XD = (size_t)MROWS * DDIM * 2;  // 16 MiB
  const size_t SZ_W  = (size_t)DDIM * DDIM * 2;   // 8 MiB

  char* p = (char*)d_ws;
  auto alloc = [&](size_t bytes) {
    char* r = p;
    p += (bytes + 255) & ~(size_t)255;
    return r;
  };
  u16* Xh  = (u16*)alloc(SZ_XD);
  u16* Xl  = (u16*)alloc(SZ_XD);
  u16* Wbh = (u16*)alloc(SZ_W);   // W staging region, reused per weight
  u16* Wbl = (u16*)alloc(SZ_W);
  u16* Qh  = (u16*)alloc(SZ_XD);
  u16* Kh  = (u16*)alloc(SZ_XD);
  u16* Kl  = (u16*)alloc(SZ_XD);
  u16* Vb  = (u16*)alloc(SZ_XD);
  u16* Vt  = Xh;   // Xh dead after V projection
  u16* ctx = Qh;   // each attn block reads exactly the Q panel it overwrites

  split_x<<<(MROWS * DDIM) / 1024, 256, 0, stream>>>(X, Xh, Xl);

  dim3 tb(32, 8);
  dim3 gg(DDIM / 128, MROWS / 128);

  transpose_w<<<dim3(64, 64), tb, 0, stream>>>(Wq, Wbh, Wbl);
  gemm3_kernel<false><<<gg, 256, 0, stream>>>(Xh, Xl, Wbh, Wbl, Qh, nullptr);

  transpose_w<<<dim3(64, 64), tb, 0, stream>>>(Wk, Wbh, Wbl);
  gemm3_kernel<true><<<gg, 256, 0, stream>>>(Xh, Xl, Wbh, Wbl, Kh, Kl);

  transpose_w<<<dim3(64, 64), tb, 0, stream>>>(Wv, Wbh, nullptr);
  gemm_kernel<0><<<gg, 256, 0, stream>>>(Xh, Wbh, Vb, nullptr);

  transpose_v<<<dim3(SEQ / 32, HD / 32, BATCH * NH), tb, 0, stream>>>(Vb, Vt);

  transpose_w<<<dim3(64, 64), tb, 0, stream>>>(Wo, Wbh, nullptr);

  attn_kernel<<<dim3(32, 32), 256, 0, stream>>>(Qh, Kh, Kl, Vt, ctx);

  gemm_kernel<2><<<gg, 256, 0, stream>>>(ctx, Wbh, out, bo);
}

// Round 4
// 611.344 us; speedup vs baseline: 1.9135x; 1.0369x over previous
//
#include <hip/hip_runtime.h>
#include <hip/hip_bf16.h>
#include <math.h>

// ---------------- problem constants ----------------
#define BATCH 2
#define SEQ   2048
#define DDIM  2048
#define NH    16
#define HD    128
#define MROWS (BATCH * SEQ)   // 4096

typedef unsigned short u16;
typedef __bf16 bf16x8 __attribute__((ext_vector_type(8)));
typedef float  f32x4  __attribute__((ext_vector_type(4)));

// round-to-nearest-even f32 -> bf16 bits
__device__ __forceinline__ u16 f2bf(float f) {
  unsigned int u = __float_as_uint(f);
  u += 0x7fffu + ((u >> 16) & 1u);
  return (u16)(u >> 16);
}
__device__ __forceinline__ float bf2f(u16 h) {
  return __uint_as_float(((unsigned int)h) << 16);
}

// async global->LDS, 16B per lane; LDS dest is wave-uniform base + lane*16
__device__ __forceinline__ void gload16(const void* g, void* s) {
  __builtin_amdgcn_global_load_lds((const __attribute__((address_space(1))) void*)g,
                                   (__attribute__((address_space(3))) void*)s, 16, 0, 0);
}

// ---------------- X f32 -> (hi, lo) bf16 pair ----------------
__global__ void split_x(const float* __restrict__ in, u16* __restrict__ hi,
                        u16* __restrict__ lo) {
  const int i = blockIdx.x * blockDim.x + threadIdx.x;   // one float4 per thread
  float4 v = ((const float4*)in)[i];
  ushort4 h, l;
  h.x = f2bf(v.x); l.x = f2bf(v.x - bf2f(h.x));
  h.y = f2bf(v.y); l.y = f2bf(v.y - bf2f(h.y));
  h.z = f2bf(v.z); l.z = f2bf(v.z - bf2f(h.z));
  h.w = f2bf(v.w); l.w = f2bf(v.w - bf2f(h.w));
  ((ushort4*)hi)[i] = h;
  ((ushort4*)lo)[i] = l;
}

// ---------------- W [K][N] f32 -> Wt [N][K] bf16 (hi [+ lo]) ----------------
__global__ void transpose_w(const float* __restrict__ W, u16* __restrict__ Wth,
                            u16* __restrict__ Wtl) {
  __shared__ float t[32][33];
  const int tx = threadIdx.x, ty = threadIdx.y;          // 32 x 8
  const int c0 = blockIdx.x * 32, r0 = blockIdx.y * 32;  // c0: n, r0: k
#pragma unroll
  for (int i = 0; i < 4; ++i)
    t[ty + i * 8][tx] = W[(size_t)(r0 + ty + i * 8) * DDIM + c0 + tx];
  __syncthreads();
#pragma unroll
  for (int i = 0; i < 4; ++i) {
    const float v = t[tx][ty + i * 8];
    const u16 h = f2bf(v);
    const size_t idx = (size_t)(c0 + ty + i * 8) * DDIM + r0 + tx;
    Wth[idx] = h;
    if (Wtl) Wtl[idx] = f2bf(v - bf2f(h));
  }
}

// ---------------- V [B*S][D] bf16 -> Vt [B*H][HD][S] bf16 ----------------
__global__ void transpose_v(const u16* __restrict__ V, u16* __restrict__ Vt) {
  __shared__ u16 t[32][33];
  const int tx = threadIdx.x, ty = threadIdx.y;          // 32 x 8
  const int s0 = blockIdx.x * 32;
  const int d0 = blockIdx.y * 32;
  const int bh = blockIdx.z;
  const int b = bh >> 4, h = bh & 15;
#pragma unroll
  for (int i = 0; i < 4; ++i)
    t[ty + i * 8][tx] = V[(size_t)(b * SEQ + s0 + ty + i * 8) * DDIM + h * HD + d0 + tx];
  __syncthreads();
#pragma unroll
  for (int i = 0; i < 4; ++i)
    Vt[((size_t)bh * HD + d0 + ty + i * 8) * SEQ + s0 + tx] = t[tx][ty + i * 8];
}

// ---------------- single-term GEMM: C[M,N] = A[M,K] x Bt[N,K]^T ----------------
template <int MODE>
__global__ __launch_bounds__(256)
void gemm_kernel(const u16* __restrict__ A, const u16* __restrict__ Bt,
                 void* __restrict__ Cout, const float* __restrict__ bias) {
  constexpr int K = DDIM, N = DDIM;
  __shared__ __align__(16) u16 As[128 * 64];
  __shared__ __align__(16) u16 Bs[128 * 64];
  const int tid = threadIdx.x;
  const int wave = tid >> 6;
  const int lane = tid & 63;
  const int lr = lane & 15, lg = lane >> 4;
  const int bm = blockIdx.y * 128, bn = blockIdx.x * 128;
  const int wr = wave >> 1, wc = wave & 1;

  f32x4 acc[4][4] = {};

  const int srow = wave * 32 + (lane >> 3);
  const int scol = (lane & 7) * 8;
  const u16* Ag = A  + (size_t)(bm + srow) * K + scol;
  const u16* Bg = Bt + (size_t)(bn + srow) * K + scol;

  for (int k0 = 0; k0 < K; k0 += 64) {
    __syncthreads();
#pragma unroll
    for (int it = 0; it < 4; ++it) {
      gload16(Ag + (size_t)it * 8 * K + k0, &As[(wave * 32 + it * 8) * 64]);
      gload16(Bg + (size_t)it * 8 * K + k0, &Bs[(wave * 32 + it * 8) * 64]);
    }
    __syncthreads();
#pragma unroll
    for (int kk = 0; kk < 64; kk += 32) {
      bf16x8 af[4], bfr[4];
#pragma unroll
      for (int i = 0; i < 4; ++i)
        af[i] = *(const bf16x8*)&As[(wr * 64 + i * 16 + lr) * 64 + kk + lg * 8];
#pragma unroll
      for (int j = 0; j < 4; ++j)
        bfr[j] = *(const bf16x8*)&Bs[(wc * 64 + j * 16 + lr) * 64 + kk + lg * 8];
#pragma unroll
      for (int i = 0; i < 4; ++i)
#pragma unroll
        for (int j = 0; j < 4; ++j)
          acc[i][j] = __builtin_amdgcn_mfma_f32_16x16x32_bf16(af[i], bfr[j], acc[i][j], 0, 0, 0);
    }
  }

#pragma unroll
  for (int i = 0; i < 4; ++i) {
    const int row0 = bm + wr * 64 + i * 16 + lg * 4;
#pragma unroll
    for (int j = 0; j < 4; ++j) {
      const int col = bn + wc * 64 + j * 16 + lr;
#pragma unroll
      for (int e = 0; e < 4; ++e) {
        const int row = row0 + e;
        const float v = acc[i][j][e];
        if constexpr (MODE == 0) {
          ((u16*)Cout)[(size_t)row * N + col] = f2bf(v);
        } else {
          ((float*)Cout)[(size_t)row * N + col] = v + bias[col];
        }
      }
    }
  }
}

// ---------------- 3-term split GEMM: C = (Ah+Al) x (Bh+Bl)^T, drop Al*Bl ----------------
template <bool WRITE_LO>
__global__ __launch_bounds__(256)
void gemm3_kernel(const u16* __restrict__ Ah, const u16* __restrict__ Al,
                  const u16* __restrict__ Bh, const u16* __restrict__ Bl,
                  u16* __restrict__ Ch, u16* __restrict__ Cl) {
  constexpr int K = DDIM, N = DDIM;
  __shared__ __align__(16) u16 Ash[128 * 64];
  __shared__ __align__(16) u16 Asl[128 * 64];
  __shared__ __align__(16) u16 Bsh[128 * 64];
  __shared__ __align__(16) u16 Bsl[128 * 64];
  const int tid = threadIdx.x;
  const int wave = tid >> 6;
  const int lane = tid & 63;
  const int lr = lane & 15, lg = lane >> 4;
  const int bm = blockIdx.y * 128, bn = blockIdx.x * 128;
  const int wr = wave >> 1, wc = wave & 1;

  f32x4 acc[4][4] = {};

  const int srow = wave * 32 + (lane >> 3);
  const int scol = (lane & 7) * 8;
  const size_t aoff = (size_t)(bm + srow) * K + scol;
  const size_t boff = (size_t)(bn + srow) * K + scol;

  for (int k0 = 0; k0 < K; k0 += 64) {
    __syncthreads();
#pragma unroll
    for (int it = 0; it < 4; ++it) {
      const size_t ro = (size_t)it * 8 * K + k0;
      const int ls = (wave * 32 + it * 8) * 64;
      gload16(Ah + aoff + ro, &Ash[ls]);
      gload16(Al + aoff + ro, &Asl[ls]);
      gload16(Bh + boff + ro, &Bsh[ls]);
      gload16(Bl + boff + ro, &Bsl[ls]);
    }
    __syncthreads();
#pragma unroll
    for (int kk = 0; kk < 64; kk += 32) {
      bf16x8 ah[4], al[4], bh[4], bl[4];
#pragma unroll
      for (int i = 0; i < 4; ++i) {
        const int off = (wr * 64 + i * 16 + lr) * 64 + kk + lg * 8;
        ah[i] = *(const bf16x8*)&Ash[off];
        al[i] = *(const bf16x8*)&Asl[off];
      }
#pragma unroll
      for (int j = 0; j < 4; ++j) {
        const int off = (wc * 64 + j * 16 + lr) * 64 + kk + lg * 8;
        bh[j] = *(const bf16x8*)&Bsh[off];
        bl[j] = *(const bf16x8*)&Bsl[off];
      }
#pragma unroll
      for (int i = 0; i < 4; ++i)
#pragma unroll
        for (int j = 0; j < 4; ++j) {
          acc[i][j] = __builtin_amdgcn_mfma_f32_16x16x32_bf16(ah[i], bh[j], acc[i][j], 0, 0, 0);
          acc[i][j] = __builtin_amdgcn_mfma_f32_16x16x32_bf16(ah[i], bl[j], acc[i][j], 0, 0, 0);
          acc[i][j] = __builtin_amdgcn_mfma_f32_16x16x32_bf16(al[i], bh[j], acc[i][j], 0, 0, 0);
        }
    }
  }

#pragma unroll
  for (int i = 0; i < 4; ++i) {
    const int row0 = bm + wr * 64 + i * 16 + lg * 4;
#pragma unroll
    for (int j = 0; j < 4; ++j) {
      const int col = bn + wc * 64 + j * 16 + lr;
#pragma unroll
      for (int e = 0; e < 4; ++e) {
        const float v = acc[i][j][e];
        const u16 h = f2bf(v);
        const size_t idx = (size_t)(row0 + e) * N + col;
        Ch[idx] = h;
        if constexpr (WRITE_LO) Cl[idx] = f2bf(v - bf2f(h));
      }
    }
  }
}

// ---------------- causal flash attention v3 ----------------
// 512 blocks x 512 threads (8 waves, 16 q-rows each -> 128 q-rows/block).
// KVBLK=64 double-buffered in LDS (Kh, Kl swizzled rows 256B; V swizzled rows 128B).
// Online softmax with: l-accumulation via MFMA (ones B-operand), defer-max (THR=8),
// fully-unmasked fast path, setprio around MFMA clusters.
__global__ __launch_bounds__(512, 1)
void attn_kernel(const u16* __restrict__ Qh, const u16* __restrict__ Khp,
                 const u16* __restrict__ Klp, const u16* __restrict__ Vt,
                 u16* __restrict__ ctx) {
  __shared__ __align__(16) u16 Ksh[2][64 * 128];   // [key][d]  rows 256B, swz (r&7)<<4
  __shared__ __align__(16) u16 Ksl[2][64 * 128];
  __shared__ __align__(16) u16 Vs [2][128 * 64];   // [d][key]  rows 128B, swz (d&7)<<4
  __shared__ __align__(16) u16 P_lds[8][16 * 32];  // [q][key]  rows 64B,  swz (q&3)<<4
  const int tid = threadIdx.x;
  const int wave = tid >> 6, lane = tid & 63;
  const int lr = lane & 15, lg = lane >> 4;

  // XCD-chunk swizzle (512 blocks, 8 XCDs -> 64-block chunks = 4 heads/XCD)
  // + descending q-panel order (LPT scheduling of the causal imbalance).
  const int id = blockIdx.y * 16 + blockIdx.x;
  const int nid = (id & 7) * 64 + (id >> 3);
  const int bh = nid >> 4;
  const int qb = 15 - (nid & 15);
  const int q0 = qb * 128;
  const int b = bh >> 4, h = bh & 15;
  const int qw = q0 + wave * 16;
  const float NEG_INF = -__builtin_inff();

  const u16* Kg = Khp + (size_t)b * SEQ * DDIM + h * HD;
  const u16* Lg = Klp + (size_t)b * SEQ * DDIM + h * HD;
  const u16* Vg = Vt + (size_t)bh * HD * SEQ;

  // Q fragments in registers: A[q=lr][k=kk*32+lg*8+e]
  bf16x8 qf[4];
#pragma unroll
  for (int kk = 0; kk < 4; ++kk)
    qf[kk] = *(const bf16x8*)&Qh[(size_t)(b * SEQ + qw + lr) * DDIM + h * HD + kk * 32 + lg * 8];

  bf16x8 ones;
#pragma unroll
  for (int i = 0; i < 8; ++i) ones[i] = (__bf16)1.0f;

  // staging geometry (per lane): K rows 256B, V rows 128B; 2 rounds each
  const int krow0 = wave * 4 + (lane >> 4);        // + it*32
  const int kcolb = (lane & 15) << 4;
  const int vrow0 = wave * 8 + (lane >> 3);        // + it*64
  const int vcolb = (lane & 7) << 4;

  auto STAGE = [&](int buf, int t) {
    const int kbase = t * 64;
#pragma unroll
    for (int it = 0; it < 2; ++it) {
      const int r = it * 32 + krow0;
      const int c = (kcolb ^ ((r & 7) << 4)) >> 1;           // elem col [0,128)
      const size_t g = (size_t)(kbase + r) * DDIM + c;
      gload16(Kg + g, &Ksh[buf][it * 4096 + wave * 512]);
      gload16(Lg + g, &Ksl[buf][it * 4096 + wave * 512]);
    }
#pragma unroll
    for (int it = 0; it < 2; ++it) {
      const int d = it * 64 + vrow0;
      const int c = (vcolb ^ ((d & 7) << 4)) >> 1;           // elem col [0,64)
      gload16(Vg + (size_t)d * SEQ + kbase + c, &Vs[buf][it * 4096 + wave * 512]);
    }
  };

  float m[4];
  f32x4 lsum = {};
#pragma unroll
  for (int e = 0; e < 4; ++e) m[e] = NEG_INF;
  f32x4 o[8] = {};

  const int nt = 2 * qb + 2;   // 64-key tiles covering keys 0 .. q0+127
  int cur = 0;
  STAGE(0, 0);
  __syncthreads();

  for (int t = 0; t < nt; ++t) {
    if (t + 1 < nt) STAGE(cur ^ 1, t + 1);
#pragma unroll
    for (int ks = 0; ks < 2; ++ks) {
      const int k0 = t * 64 + ks * 32;
      if (k0 <= qw + 15) {      // wave-uniform: skip fully-masked subtiles
        // ---- QK^T (2-term) from LDS ----
        f32x4 s[2] = {};
        __builtin_amdgcn_s_setprio(1);
#pragma unroll
        for (int fc = 0; fc < 2; ++fc) {
          const int r = ks * 32 + fc * 16 + lr;
          const int sw = (r & 7) << 4;
#pragma unroll
          for (int kk = 0; kk < 4; ++kk) {
            const int idx = r * 128 + (((kk * 64 + lg * 16) ^ sw) >> 1);
            bf16x8 kfh = *(const bf16x8*)&Ksh[cur][idx];
            bf16x8 kfl = *(const bf16x8*)&Ksl[cur][idx];
            s[fc] = __builtin_amdgcn_mfma_f32_16x16x32_bf16(qf[kk], kfh, s[fc], 0, 0, 0);
            s[fc] = __builtin_amdgcn_mfma_f32_16x16x32_bf16(qf[kk], kfl, s[fc], 0, 0, 0);
          }
        }
        __builtin_amdgcn_s_setprio(0);
        // ---- causal mask (skipped when subtile fully unmasked) ----
        if (k0 + 31 > qw) {
#pragma unroll
          for (int e = 0; e < 4; ++e) {
            const int row = qw + lg * 4 + e;
#pragma unroll
            for (int fc = 0; fc < 2; ++fc) {
              const int key = k0 + fc * 16 + lr;
              if (key > row) s[fc][e] = NEG_INF;
            }
          }
        }
        // ---- row max (4 independent shfl chains) ----
        float rm[4];
#pragma unroll
        for (int e = 0; e < 4; ++e) {
          float r0 = fmaxf(s[0][e], s[1][e]);
          r0 = fmaxf(r0, __shfl_xor(r0, 1));
          r0 = fmaxf(r0, __shfl_xor(r0, 2));
          r0 = fmaxf(r0, __shfl_xor(r0, 4));
          r0 = fmaxf(r0, __shfl_xor(r0, 8));
          rm[e] = r0;
        }
        // ---- defer-max: rescale only when some row grew past THR=8 ----
        const float need = fmaxf(fmaxf(rm[0] - m[0], rm[1] - m[1]),
                                 fmaxf(rm[2] - m[2], rm[3] - m[3]));
        if (!__all(need <= 8.0f)) {
#pragma unroll
          for (int e = 0; e < 4; ++e) {
            const float mn = fmaxf(m[e], rm[e]);
            const float al = __expf(m[e] - mn);
#pragma unroll
            for (int db = 0; db < 8; ++db) o[db][e] *= al;
            lsum[e] *= al;
            m[e] = mn;
          }
        }
        // ---- p = exp(s - m), store P to LDS (swizzled) ----
#pragma unroll
        for (int e = 0; e < 4; ++e) {
          const float p0 = __expf(s[0][e] - m[e]);
          const float p1 = __expf(s[1][e] - m[e]);
          const int q = lg * 4 + e;
          const int sw = (q & 3) << 4;
          P_lds[wave][q * 32 + ((((lr) * 2) ^ sw) >> 1)] = f2bf(p0);
          P_lds[wave][q * 32 + ((((16 + lr) * 2) ^ sw) >> 1)] = f2bf(p1);
        }
        __builtin_amdgcn_wave_barrier();
        bf16x8 pf = *(const bf16x8*)&P_lds[wave][lr * 32 + (((lg * 16) ^ ((lr & 3) << 4)) >> 1)];
        __builtin_amdgcn_wave_barrier();
        // ---- PV + l-accumulation via MFMA ----
        __builtin_amdgcn_s_setprio(1);
#pragma unroll
        for (int db = 0; db < 8; ++db) {
          const int d = db * 16 + lr;
          const int idx = d * 64 + (((ks * 64 + lg * 16) ^ ((d & 7) << 4)) >> 1);
          bf16x8 vf = *(const bf16x8*)&Vs[cur][idx];
          o[db] = __builtin_amdgcn_mfma_f32_16x16x32_bf16(pf, vf, o[db], 0, 0, 0);
        }
        lsum = __builtin_amdgcn_mfma_f32_16x16x32_bf16(pf, ones, lsum, 0, 0, 0);
        __builtin_amdgcn_s_setprio(0);
      }
    }
    __syncthreads();   // drains prefetch vmcnt + protects LDS buffer reuse
    cur ^= 1;
  }

  // epilogue: ctx = o / lsum
#pragma unroll
  for (int db = 0; db < 8; ++db)
#pragma unroll
    for (int e = 0; e < 4; ++e) {
      const float v = o[db][e] / lsum[e];
      ctx[(size_t)(b * SEQ + qw + lg * 4 + e) * DDIM + h * HD + db * 16 + lr] = f2bf(v);
    }
}

// ---------------- launch ----------------
extern "C" void kernel_launch(void* const* d_in, const int* in_sizes, int n_in,
                              void* d_out, int out_size, void* d_ws, size_t ws_size,
                              hipStream_t stream) {
  const float* X  = (const float*)d_in[0];
  const float* Wq = (const float*)d_in[1];
  const float* Wk = (const float*)d_in[2];
  const float* Wv = (const float*)d_in[3];
  const float* Wo = (const float*)d_in[4];
  const float* bo = (const float*)d_in[5];
  float* out = (float*)d_out;

  const size_t SZ_XD = (size_t)MROWS * DDIM * 2;  // 16 MiB
  const size_t SZ_W  = (size_t)DDIM * DDIM * 2;   // 8 MiB

  char* p = (char*)d_ws;
  auto alloc = [&](size_t bytes) {
    char* r = p;
    p += (bytes + 255) & ~(size_t)255;
    return r;
  };
  u16* Xh  = (u16*)alloc(SZ_XD);
  u16* Xl  = (u16*)alloc(SZ_XD);
  u16* Wbh = (u16*)alloc(SZ_W);   // W staging region, reused per weight
  u16* Wbl = (u16*)alloc(SZ_W);
  u16* Qh  = (u16*)alloc(SZ_XD);
  u16* Kh  = (u16*)alloc(SZ_XD);
  u16* Kl  = (u16*)alloc(SZ_XD);
  u16* Vb  = (u16*)alloc(SZ_XD);
  u16* Vt  = Xh;   // Xh dead after V projection
  u16* ctx = Qh;   // each attn block reads exactly the Q panel it overwrites

  split_x<<<(MROWS * DDIM) / 1024, 256, 0, stream>>>(X, Xh, Xl);

  dim3 tb(32, 8);
  dim3 gg(DDIM / 128, MROWS / 128);

  transpose_w<<<dim3(64, 64), tb, 0, stream>>>(Wq, Wbh, Wbl);
  gemm3_kernel<false><<<gg, 256, 0, stream>>>(Xh, Xl, Wbh, Wbl, Qh, nullptr);

  transpose_w<<<dim3(64, 64), tb, 0, stream>>>(Wk, Wbh, Wbl);
  gemm3_kernel<true><<<gg, 256, 0, stream>>>(Xh, Xl, Wbh, Wbl, Kh, Kl);

  transpose_w<<<dim3(64, 64), tb, 0, stream>>>(Wv, Wbh, nullptr);
  gemm_kernel<0><<<gg, 256, 0, stream>>>(Xh, Wbh, Vb, nullptr);

  transpose_v<<<dim3(SEQ / 32, HD / 32, BATCH * NH), tb, 0, stream>>>(Vb, Vt);

  transpose_w<<<dim3(64, 64), tb, 0, stream>>>(Wo, Wbh, nullptr);

  attn_kernel<<<dim3(16, 32), 512, 0, stream>>>(Qh, Kh, Kl, Vt, ctx);

  gemm_kernel<2><<<gg, 256, 0, stream>>>(ctx, Wbh, out, bo);
}

// Round 5
// 593.317 us; speedup vs baseline: 1.9716x; 1.0304x over previous
//
#include <hip/hip_runtime.h>
#include <hip/hip_bf16.h>
#include <math.h>

// ---------------- problem constants ----------------
#define BATCH 2
#define SEQ   2048
#define DDIM  2048
#define NH    16
#define HD    128
#define MROWS (BATCH * SEQ)   // 4096

typedef unsigned short u16;
typedef __bf16 bf16x8 __attribute__((ext_vector_type(8)));
typedef float  f32x4  __attribute__((ext_vector_type(4)));

// round-to-nearest-even f32 -> bf16 bits
__device__ __forceinline__ u16 f2bf(float f) {
  unsigned int u = __float_as_uint(f);
  u += 0x7fffu + ((u >> 16) & 1u);
  return (u16)(u >> 16);
}
__device__ __forceinline__ float bf2f(u16 h) {
  return __uint_as_float(((unsigned int)h) << 16);
}

// async global->LDS, 16B per lane; LDS dest is wave-uniform base + lane*16
__device__ __forceinline__ void gload16(const void* g, void* s) {
  __builtin_amdgcn_global_load_lds((const __attribute__((address_space(1))) void*)g,
                                   (__attribute__((address_space(3))) void*)s, 16, 0, 0);
}

// ---------------- X f32 -> (hi, lo) bf16 pair ----------------
__global__ void split_x(const float* __restrict__ in, u16* __restrict__ hi,
                        u16* __restrict__ lo) {
  const int i = blockIdx.x * blockDim.x + threadIdx.x;   // one float4 per thread
  float4 v = ((const float4*)in)[i];
  ushort4 h, l;
  h.x = f2bf(v.x); l.x = f2bf(v.x - bf2f(h.x));
  h.y = f2bf(v.y); l.y = f2bf(v.y - bf2f(h.y));
  h.z = f2bf(v.z); l.z = f2bf(v.z - bf2f(h.z));
  h.w = f2bf(v.w); l.w = f2bf(v.w - bf2f(h.w));
  ((ushort4*)hi)[i] = h;
  ((ushort4*)lo)[i] = l;
}

// ---------------- W [K][N] f32 -> Wt [N][K] bf16 (hi [+ lo]) ----------------
__global__ void transpose_w(const float* __restrict__ W, u16* __restrict__ Wth,
                            u16* __restrict__ Wtl) {
  __shared__ float t[32][33];
  const int tx = threadIdx.x, ty = threadIdx.y;          // 32 x 8
  const int c0 = blockIdx.x * 32, r0 = blockIdx.y * 32;  // c0: n, r0: k
#pragma unroll
  for (int i = 0; i < 4; ++i)
    t[ty + i * 8][tx] = W[(size_t)(r0 + ty + i * 8) * DDIM + c0 + tx];
  __syncthreads();
#pragma unroll
  for (int i = 0; i < 4; ++i) {
    const float v = t[tx][ty + i * 8];
    const u16 h = f2bf(v);
    const size_t idx = (size_t)(c0 + ty + i * 8) * DDIM + r0 + tx;
    Wth[idx] = h;
    if (Wtl) Wtl[idx] = f2bf(v - bf2f(h));
  }
}

// ---------------- V [B*S][D] bf16 -> Vt [B*H][HD][S] bf16 ----------------
__global__ void transpose_v(const u16* __restrict__ V, u16* __restrict__ Vt) {
  __shared__ u16 t[32][33];
  const int tx = threadIdx.x, ty = threadIdx.y;          // 32 x 8
  const int s0 = blockIdx.x * 32;
  const int d0 = blockIdx.y * 32;
  const int bh = blockIdx.z;
  const int b = bh >> 4, h = bh & 15;
#pragma unroll
  for (int i = 0; i < 4; ++i)
    t[ty + i * 8][tx] = V[(size_t)(b * SEQ + s0 + ty + i * 8) * DDIM + h * HD + d0 + tx];
  __syncthreads();
#pragma unroll
  for (int i = 0; i < 4; ++i)
    Vt[((size_t)bh * HD + d0 + ty + i * 8) * SEQ + s0 + tx] = t[tx][ty + i * 8];
}

// ---------------- single-term GEMM: C[M,N] = A[M,K] x Bt[N,K]^T ----------------
template <int MODE>
__global__ __launch_bounds__(256)
void gemm_kernel(const u16* __restrict__ A, const u16* __restrict__ Bt,
                 void* __restrict__ Cout, const float* __restrict__ bias) {
  constexpr int K = DDIM, N = DDIM;
  __shared__ __align__(16) u16 As[128 * 64];
  __shared__ __align__(16) u16 Bs[128 * 64];
  const int tid = threadIdx.x;
  const int wave = tid >> 6;
  const int lane = tid & 63;
  const int lr = lane & 15, lg = lane >> 4;
  const int bm = blockIdx.y * 128, bn = blockIdx.x * 128;
  const int wr = wave >> 1, wc = wave & 1;

  f32x4 acc[4][4] = {};

  const int srow = wave * 32 + (lane >> 3);
  const int scol = (lane & 7) * 8;
  const u16* Ag = A  + (size_t)(bm + srow) * K + scol;
  const u16* Bg = Bt + (size_t)(bn + srow) * K + scol;

  for (int k0 = 0; k0 < K; k0 += 64) {
    __syncthreads();
#pragma unroll
    for (int it = 0; it < 4; ++it) {
      gload16(Ag + (size_t)it * 8 * K + k0, &As[(wave * 32 + it * 8) * 64]);
      gload16(Bg + (size_t)it * 8 * K + k0, &Bs[(wave * 32 + it * 8) * 64]);
    }
    __syncthreads();
#pragma unroll
    for (int kk = 0; kk < 64; kk += 32) {
      bf16x8 af[4], bfr[4];
#pragma unroll
      for (int i = 0; i < 4; ++i)
        af[i] = *(const bf16x8*)&As[(wr * 64 + i * 16 + lr) * 64 + kk + lg * 8];
#pragma unroll
      for (int j = 0; j < 4; ++j)
        bfr[j] = *(const bf16x8*)&Bs[(wc * 64 + j * 16 + lr) * 64 + kk + lg * 8];
#pragma unroll
      for (int i = 0; i < 4; ++i)
#pragma unroll
        for (int j = 0; j < 4; ++j)
          acc[i][j] = __builtin_amdgcn_mfma_f32_16x16x32_bf16(af[i], bfr[j], acc[i][j], 0, 0, 0);
    }
  }

#pragma unroll
  for (int i = 0; i < 4; ++i) {
    const int row0 = bm + wr * 64 + i * 16 + lg * 4;
#pragma unroll
    for (int j = 0; j < 4; ++j) {
      const int col = bn + wc * 64 + j * 16 + lr;
#pragma unroll
      for (int e = 0; e < 4; ++e) {
        const int row = row0 + e;
        const float v = acc[i][j][e];
        if constexpr (MODE == 0) {
          ((u16*)Cout)[(size_t)row * N + col] = f2bf(v);
        } else {
          ((float*)Cout)[(size_t)row * N + col] = v + bias[col];
        }
      }
    }
  }
}

// ------- split GEMM: C = A x (Bh+Bl)^T (+ Al x Bh^T if TERMS==3) -------
// TERMS=2: Q path (A-hi only; error ~ bf16 storage rounding anyway).
// TERMS=3: K path (near-fp32). WRITE_LO adds bf16 residual output.
template <int TERMS, bool WRITE_LO>
__global__ __launch_bounds__(256)
void gemm3_kernel(const u16* __restrict__ Ah, const u16* __restrict__ Al,
                  const u16* __restrict__ Bh, const u16* __restrict__ Bl,
                  u16* __restrict__ Ch, u16* __restrict__ Cl) {
  constexpr int K = DDIM, N = DDIM;
  __shared__ __align__(16) u16 Ash[128 * 64];
  __shared__ __align__(16) u16 Asl[TERMS == 3 ? 128 * 64 : 8];
  __shared__ __align__(16) u16 Bsh[128 * 64];
  __shared__ __align__(16) u16 Bsl[128 * 64];
  const int tid = threadIdx.x;
  const int wave = tid >> 6;
  const int lane = tid & 63;
  const int lr = lane & 15, lg = lane >> 4;
  const int bm = blockIdx.y * 128, bn = blockIdx.x * 128;
  const int wr = wave >> 1, wc = wave & 1;

  f32x4 acc[4][4] = {};

  const int srow = wave * 32 + (lane >> 3);
  const int scol = (lane & 7) * 8;
  const size_t aoff = (size_t)(bm + srow) * K + scol;
  const size_t boff = (size_t)(bn + srow) * K + scol;

  for (int k0 = 0; k0 < K; k0 += 64) {
    __syncthreads();
#pragma unroll
    for (int it = 0; it < 4; ++it) {
      const size_t ro = (size_t)it * 8 * K + k0;
      const int ls = (wave * 32 + it * 8) * 64;
      gload16(Ah + aoff + ro, &Ash[ls]);
      if constexpr (TERMS == 3) gload16(Al + aoff + ro, &Asl[ls]);
      gload16(Bh + boff + ro, &Bsh[ls]);
      gload16(Bl + boff + ro, &Bsl[ls]);
    }
    __syncthreads();
#pragma unroll
    for (int kk = 0; kk < 64; kk += 32) {
      bf16x8 ah[4], al[4], bh[4], bl[4];
#pragma unroll
      for (int i = 0; i < 4; ++i) {
        const int off = (wr * 64 + i * 16 + lr) * 64 + kk + lg * 8;
        ah[i] = *(const bf16x8*)&Ash[off];
        if constexpr (TERMS == 3) al[i] = *(const bf16x8*)&Asl[off];
      }
#pragma unroll
      for (int j = 0; j < 4; ++j) {
        const int off = (wc * 64 + j * 16 + lr) * 64 + kk + lg * 8;
        bh[j] = *(const bf16x8*)&Bsh[off];
        bl[j] = *(const bf16x8*)&Bsl[off];
      }
#pragma unroll
      for (int i = 0; i < 4; ++i)
#pragma unroll
        for (int j = 0; j < 4; ++j) {
          acc[i][j] = __builtin_amdgcn_mfma_f32_16x16x32_bf16(ah[i], bh[j], acc[i][j], 0, 0, 0);
          acc[i][j] = __builtin_amdgcn_mfma_f32_16x16x32_bf16(ah[i], bl[j], acc[i][j], 0, 0, 0);
          if constexpr (TERMS == 3)
            acc[i][j] = __builtin_amdgcn_mfma_f32_16x16x32_bf16(al[i], bh[j], acc[i][j], 0, 0, 0);
        }
    }
  }

#pragma unroll
  for (int i = 0; i < 4; ++i) {
    const int row0 = bm + wr * 64 + i * 16 + lg * 4;
#pragma unroll
    for (int j = 0; j < 4; ++j) {
      const int col = bn + wc * 64 + j * 16 + lr;
#pragma unroll
      for (int e = 0; e < 4; ++e) {
        const float v = acc[i][j][e];
        const u16 h = f2bf(v);
        const size_t idx = (size_t)(row0 + e) * N + col;
        Ch[idx] = h;
        if constexpr (WRITE_LO) Cl[idx] = f2bf(v - bf2f(h));
      }
    }
  }
}

// ---------------- causal flash attention v3 ----------------
// 512 blocks x 512 threads (8 waves, 16 q-rows each -> 128 q-rows/block).
// KVBLK=64 double-buffered in LDS; l via MFMA-ones; defer-max THR=8.
// Complementary per-CU qb pairing: CU c runs (qb=15-(c&15)) then (qb=(c&15)),
// so every CU does exactly 68 subtile-steps (fixes the 2x makespan skew).
__global__ __launch_bounds__(512, 1)
void attn_kernel(const u16* __restrict__ Qh, const u16* __restrict__ Khp,
                 const u16* __restrict__ Klp, const u16* __restrict__ Vt,
                 u16* __restrict__ ctx) {
  __shared__ __align__(16) u16 Ksh[2][64 * 128];   // [key][d]  rows 256B, swz (r&7)<<4
  __shared__ __align__(16) u16 Ksl[2][64 * 128];
  __shared__ __align__(16) u16 Vs [2][128 * 64];   // [d][key]  rows 128B, swz (d&7)<<4
  __shared__ __align__(16) u16 P_lds[8][16 * 32];  // [q][key]  rows 64B,  swz (q&3)<<4
  const int tid = threadIdx.x;
  const int wave = tid >> 6, lane = tid & 63;
  const int lr = lane & 15, lg = lane >> 4;

  // XCD chunking (id&7 -> XCD) + complementary qb pairing within each chunk.
  const int id = blockIdx.y * 16 + blockIdx.x;
  const int xcd = id & 7;
  const int j = id >> 3;                  // 0..63 within chunk
  int bh, qb;
  if (j < 32) { bh = xcd * 4 + (j >> 4);            qb = 15 - (j & 15); }
  else        { const int jj = j - 32;
                bh = xcd * 4 + 2 + (jj >> 4);       qb = jj & 15; }
  const int q0 = qb * 128;
  const int b = bh >> 4, h = bh & 15;
  const int qw = q0 + wave * 16;
  const float NEG_INF = -__builtin_inff();

  const u16* Kg = Khp + (size_t)b * SEQ * DDIM + h * HD;
  const u16* Lg = Klp + (size_t)b * SEQ * DDIM + h * HD;
  const u16* Vg = Vt + (size_t)bh * HD * SEQ;

  // Q fragments in registers: A[q=lr][k=kk*32+lg*8+e]
  bf16x8 qf[4];
#pragma unroll
  for (int kk = 0; kk < 4; ++kk)
    qf[kk] = *(const bf16x8*)&Qh[(size_t)(b * SEQ + qw + lr) * DDIM + h * HD + kk * 32 + lg * 8];

  bf16x8 ones;
#pragma unroll
  for (int i = 0; i < 8; ++i) ones[i] = (__bf16)1.0f;

  // staging geometry (per lane): K rows 256B, V rows 128B; 2 rounds each
  const int krow0 = wave * 4 + (lane >> 4);        // + it*32
  const int kcolb = (lane & 15) << 4;
  const int vrow0 = wave * 8 + (lane >> 3);        // + it*64
  const int vcolb = (lane & 7) << 4;

  auto STAGE = [&](int buf, int t) {
    const int kbase = t * 64;
#pragma unroll
    for (int it = 0; it < 2; ++it) {
      const int r = it * 32 + krow0;
      const int c = (kcolb ^ ((r & 7) << 4)) >> 1;           // elem col [0,128)
      const size_t g = (size_t)(kbase + r) * DDIM + c;
      gload16(Kg + g, &Ksh[buf][it * 4096 + wave * 512]);
      gload16(Lg + g, &Ksl[buf][it * 4096 + wave * 512]);
    }
#pragma unroll
    for (int it = 0; it < 2; ++it) {
      const int d = it * 64 + vrow0;
      const int c = (vcolb ^ ((d & 7) << 4)) >> 1;           // elem col [0,64)
      gload16(Vg + (size_t)d * SEQ + kbase + c, &Vs[buf][it * 4096 + wave * 512]);
    }
  };

  float m[4];
  f32x4 lsum = {};
#pragma unroll
  for (int e = 0; e < 4; ++e) m[e] = NEG_INF;
  f32x4 o[8] = {};

  const int nt = 2 * qb + 2;   // 64-key tiles covering keys 0 .. q0+127
  int cur = 0;
  STAGE(0, 0);
  __syncthreads();

  for (int t = 0; t < nt; ++t) {
    if (t + 1 < nt) STAGE(cur ^ 1, t + 1);
#pragma unroll
    for (int ks = 0; ks < 2; ++ks) {
      const int k0 = t * 64 + ks * 32;
      if (k0 <= qw + 15) {      // wave-uniform: skip fully-masked subtiles
        // ---- QK^T (2-term) from LDS ----
        f32x4 s[2] = {};
        __builtin_amdgcn_s_setprio(1);
#pragma unroll
        for (int fc = 0; fc < 2; ++fc) {
          const int r = ks * 32 + fc * 16 + lr;
          const int sw = (r & 7) << 4;
#pragma unroll
          for (int kk = 0; kk < 4; ++kk) {
            const int idx = r * 128 + (((kk * 64 + lg * 16) ^ sw) >> 1);
            bf16x8 kfh = *(const bf16x8*)&Ksh[cur][idx];
            bf16x8 kfl = *(const bf16x8*)&Ksl[cur][idx];
            s[fc] = __builtin_amdgcn_mfma_f32_16x16x32_bf16(qf[kk], kfh, s[fc], 0, 0, 0);
            s[fc] = __builtin_amdgcn_mfma_f32_16x16x32_bf16(qf[kk], kfl, s[fc], 0, 0, 0);
          }
        }
        __builtin_amdgcn_s_setprio(0);
        // ---- causal mask (skipped when subtile fully unmasked) ----
        if (k0 + 31 > qw) {
#pragma unroll
          for (int e = 0; e < 4; ++e) {
            const int row = qw + lg * 4 + e;
#pragma unroll
            for (int fc = 0; fc < 2; ++fc) {
              const int key = k0 + fc * 16 + lr;
              if (key > row) s[fc][e] = NEG_INF;
            }
          }
        }
        // ---- row max (4 independent shfl chains) ----
        float rm[4];
#pragma unroll
        for (int e = 0; e < 4; ++e) {
          float r0 = fmaxf(s[0][e], s[1][e]);
          r0 = fmaxf(r0, __shfl_xor(r0, 1));
          r0 = fmaxf(r0, __shfl_xor(r0, 2));
          r0 = fmaxf(r0, __shfl_xor(r0, 4));
          r0 = fmaxf(r0, __shfl_xor(r0, 8));
          rm[e] = r0;
        }
        // ---- defer-max: rescale only when some row grew past THR=8 ----
        const float need = fmaxf(fmaxf(rm[0] - m[0], rm[1] - m[1]),
                                 fmaxf(rm[2] - m[2], rm[3] - m[3]));
        if (!__all(need <= 8.0f)) {
#pragma unroll
          for (int e = 0; e < 4; ++e) {
            const float mn = fmaxf(m[e], rm[e]);
            const float al = __expf(m[e] - mn);
#pragma unroll
            for (int db = 0; db < 8; ++db) o[db][e] *= al;
            lsum[e] *= al;
            m[e] = mn;
          }
        }
        // ---- p = exp(s - m), store P to LDS (swizzled) ----
#pragma unroll
        for (int e = 0; e < 4; ++e) {
          const float p0 = __expf(s[0][e] - m[e]);
          const float p1 = __expf(s[1][e] - m[e]);
          const int q = lg * 4 + e;
          const int sw = (q & 3) << 4;
          P_lds[wave][q * 32 + ((((lr) * 2) ^ sw) >> 1)] = f2bf(p0);
          P_lds[wave][q * 32 + ((((16 + lr) * 2) ^ sw) >> 1)] = f2bf(p1);
        }
        __builtin_amdgcn_wave_barrier();
        bf16x8 pf = *(const bf16x8*)&P_lds[wave][lr * 32 + (((lg * 16) ^ ((lr & 3) << 4)) >> 1)];
        __builtin_amdgcn_wave_barrier();
        // ---- PV + l-accumulation via MFMA ----
        __builtin_amdgcn_s_setprio(1);
#pragma unroll
        for (int db = 0; db < 8; ++db) {
          const int d = db * 16 + lr;
          const int idx = d * 64 + (((ks * 64 + lg * 16) ^ ((d & 7) << 4)) >> 1);
          bf16x8 vf = *(const bf16x8*)&Vs[cur][idx];
          o[db] = __builtin_amdgcn_mfma_f32_16x16x32_bf16(pf, vf, o[db], 0, 0, 0);
        }
        lsum = __builtin_amdgcn_mfma_f32_16x16x32_bf16(pf, ones, lsum, 0, 0, 0);
        __builtin_amdgcn_s_setprio(0);
      }
    }
    __syncthreads();   // drains prefetch vmcnt + protects LDS buffer reuse
    cur ^= 1;
  }

  // epilogue: ctx = o / lsum
#pragma unroll
  for (int db = 0; db < 8; ++db)
#pragma unroll
    for (int e = 0; e < 4; ++e) {
      const float v = o[db][e] / lsum[e];
      ctx[(size_t)(b * SEQ + qw + lg * 4 + e) * DDIM + h * HD + db * 16 + lr] = f2bf(v);
    }
}

// ---------------- launch ----------------
extern "C" void kernel_launch(void* const* d_in, const int* in_sizes, int n_in,
                              void* d_out, int out_size, void* d_ws, size_t ws_size,
                              hipStream_t stream) {
  const float* X  = (const float*)d_in[0];
  const float* Wq = (const float*)d_in[1];
  const float* Wk = (const float*)d_in[2];
  const float* Wv = (const float*)d_in[3];
  const float* Wo = (const float*)d_in[4];
  const float* bo = (const float*)d_in[5];
  float* out = (float*)d_out;

  const size_t SZ_XD = (size_t)MROWS * DDIM * 2;  // 16 MiB
  const size_t SZ_W  = (size_t)DDIM * DDIM * 2;   // 8 MiB

  char* p = (char*)d_ws;
  auto alloc = [&](size_t bytes) {
    char* r = p;
    p += (bytes + 255) & ~(size_t)255;
    return r;
  };
  u16* Xh  = (u16*)alloc(SZ_XD);
  u16* Xl  = (u16*)alloc(SZ_XD);
  u16* Wbh = (u16*)alloc(SZ_W);   // W staging region, reused per weight
  u16* Wbl = (u16*)alloc(SZ_W);
  u16* Qh  = (u16*)alloc(SZ_XD);
  u16* Kh  = (u16*)alloc(SZ_XD);
  u16* Kl  = (u16*)alloc(SZ_XD);
  u16* Vb  = (u16*)alloc(SZ_XD);
  u16* Vt  = Xh;   // Xh dead after V projection
  u16* ctx = Qh;   // each attn block reads exactly the Q panel it overwrites

  split_x<<<(MROWS * DDIM) / 1024, 256, 0, stream>>>(X, Xh, Xl);

  dim3 tb(32, 8);
  dim3 gg(DDIM / 128, MROWS / 128);

  transpose_w<<<dim3(64, 64), tb, 0, stream>>>(Wq, Wbh, Wbl);
  gemm3_kernel<2, false><<<gg, 256, 0, stream>>>(Xh, Xl, Wbh, Wbl, Qh, nullptr);

  transpose_w<<<dim3(64, 64), tb, 0, stream>>>(Wk, Wbh, Wbl);
  gemm3_kernel<3, true><<<gg, 256, 0, stream>>>(Xh, Xl, Wbh, Wbl, Kh, Kl);

  transpose_w<<<dim3(64, 64), tb, 0, stream>>>(Wv, Wbh, nullptr);
  gemm_kernel<0><<<gg, 256, 0, stream>>>(Xh, Wbh, Vb, nullptr);

  transpose_v<<<dim3(SEQ / 32, HD / 32, BATCH * NH), tb, 0, stream>>>(Vb, Vt);

  transpose_w<<<dim3(64, 64), tb, 0, stream>>>(Wo, Wbh, nullptr);

  attn_kernel<<<dim3(16, 32), 512, 0, stream>>>(Qh, Kh, Kl, Vt, ctx);

  gemm_kernel<2><<<gg, 256, 0, stream>>>(ctx, Wbh, out, bo);
}